// Round 1
// baseline (77.534 us; speedup 1.0000x reference)
//
#include <hip/hip_runtime.h>
#include <math.h>

#define HW   524288u     // 512*1024  (= 2^19)
#define NPIX 2097152u    // 4*512*1024
#define NCH  19
#define NC   12

// ---- per-pixel evaluation: 19 logits -> (sum of 12 plane values squared, argmax plane)
__device__ __forceinline__ void pixel_eval(const float* __restrict__ p,
                                           float& s2, int& pred) {
    float m = p[0];
    #pragma unroll
    for (int c = 1; c < NCH; ++c) m = fmaxf(m, p[c]);
    float e[NCH];
    float Z = 0.f;
    #pragma unroll
    for (int c = 0; c < NCH; ++c) { e[c] = __expf(p[c] - m); Z += e[c]; }
    float invZ = 1.0f / Z;

    float o[NC];
    // IDS_MAPPING = [[0],[1],[2,3,4],[5],[6,7],[8,9,10],[11],[12],[13,14,15],[16],[17],[18]]
    o[0]  = e[0]  * invZ;
    o[1]  = e[1]  * invZ;
    o[2]  = p[2] + p[3] + p[4];
    o[3]  = e[5]  * invZ;
    o[4]  = p[6] + p[7];
    o[5]  = p[8] + p[9] + p[10];
    o[6]  = e[11] * invZ;
    o[7]  = e[12] * invZ;
    o[8]  = p[13] + p[14] + p[15];
    o[9]  = e[16] * invZ;
    o[10] = e[17] * invZ;
    o[11] = e[18] * invZ;

    float best = o[0]; int bi = 0; float acc = 0.f;
    #pragma unroll
    for (int k = 0; k < NC; ++k) {
        acc += o[k] * o[k];
        if (o[k] > best) { best = o[k]; bi = k; }  // strict > keeps first-max semantics
    }
    s2 = acc; pred = bi;
}

// ---- pass 1: per-class histogram count + per-class sum of s2
__global__ __launch_bounds__(256) void msiwc_pass1(const float* __restrict__ x,
                                                   float* __restrict__ ws) {
    __shared__ float s_cnt[NC];
    __shared__ float s_sum[NC];
    if (threadIdx.x < NC) { s_cnt[threadIdx.x] = 0.f; s_sum[threadIdx.x] = 0.f; }
    __syncthreads();

    unsigned t  = blockIdx.x * blockDim.x + threadIdx.x;   // 0 .. NPIX/4-1
    unsigned p0 = t * 4u;                                  // first of 4 pixels
    unsigned n  = p0 >> 19;                                // pixel / (H*W)
    unsigned hw = p0 & (HW - 1u);
    const float* base = x + (size_t)n * NCH * HW + hw;

    float4 v[NCH];
    #pragma unroll
    for (int c = 0; c < NCH; ++c)
        v[c] = *reinterpret_cast<const float4*>(base + (size_t)c * HW);

    #pragma unroll
    for (int j = 0; j < 4; ++j) {
        float pv[NCH];
        #pragma unroll
        for (int c = 0; c < NCH; ++c) {
            // j is a compile-time constant after unroll -> folds to .x/.y/.z/.w
            pv[c] = (j == 0) ? v[c].x : (j == 1) ? v[c].y : (j == 2) ? v[c].z : v[c].w;
        }
        float s2; int pred;
        pixel_eval(pv, s2, pred);
        atomicAdd(&s_cnt[pred], 1.0f);
        atomicAdd(&s_sum[pred], s2);
    }

    __syncthreads();
    if (threadIdx.x < NC) {
        atomicAdd(&ws[threadIdx.x],      s_cnt[threadIdx.x]);
        atomicAdd(&ws[NC + threadIdx.x], s_sum[threadIdx.x]);
    }
}

// ---- pass 2: weights from histogram, final scalar
__global__ void msiwc_pass2(const float* __restrict__ ws, float* __restrict__ out) {
    __shared__ float terms[NC];
    int k = threadIdx.x;
    if (k < NC) {
        double hist = (double)ws[k];
        double w = pow(hist, 0.2) * pow((double)NPIX, 0.8);
        if (w < 1.0) w = 1.0;
        terms[k] = (float)((double)ws[NC + k] / w);
    }
    __syncthreads();
    if (k == 0) {
        float tot = 0.f;
        #pragma unroll
        for (int i = 0; i < NC; ++i) tot += terms[i];
        out[0] = -tot / 48.0f;   // N*C = 4*12
    }
}

extern "C" void kernel_launch(void* const* d_in, const int* in_sizes, int n_in,
                              void* d_out, int out_size, void* d_ws, size_t ws_size,
                              hipStream_t stream) {
    const float* x = (const float*)d_in[0];
    float* ws = (float*)d_ws;

    // ws is poisoned once (0xAA) and NOT re-poisoned between graph replays:
    // zero the 24 accumulators every call.
    hipMemsetAsync(ws, 0, 2 * NC * sizeof(float), stream);

    msiwc_pass1<<<NPIX / (256 * 4), 256, 0, stream>>>(x, ws);
    msiwc_pass2<<<1, 64, 0, stream>>>(ws, (float*)d_out);
}

// Round 2
// 43.872 us; speedup vs baseline: 1.7673x; 1.7673x over previous
//
#include <hip/hip_runtime.h>
#include <math.h>

#define HW    524288u     // 512*1024  (= 2^19)
#define NPIX  2097152u    // 4*512*1024
#define NCH   19
#define NC    12
#define BLK   256
#define GRID  1024
#define ITERS 2           // (NPIX/4) / (BLK*GRID)

// ---- per-pixel evaluation: 19 logits -> (sum of 12 plane values squared, argmax plane)
__device__ __forceinline__ void pixel_eval(const float* __restrict__ p,
                                           float& s2, int& pred) {
    float m = p[0];
    #pragma unroll
    for (int c = 1; c < NCH; ++c) m = fmaxf(m, p[c]);
    float e[NCH];
    float Z = 0.f;
    #pragma unroll
    for (int c = 0; c < NCH; ++c) { e[c] = __expf(p[c] - m); Z += e[c]; }
    float invZ = 1.0f / Z;

    float o[NC];
    // IDS_MAPPING = [[0],[1],[2,3,4],[5],[6,7],[8,9,10],[11],[12],[13,14,15],[16],[17],[18]]
    o[0]  = e[0]  * invZ;
    o[1]  = e[1]  * invZ;
    o[2]  = p[2] + p[3] + p[4];
    o[3]  = e[5]  * invZ;
    o[4]  = p[6] + p[7];
    o[5]  = p[8] + p[9] + p[10];
    o[6]  = e[11] * invZ;
    o[7]  = e[12] * invZ;
    o[8]  = p[13] + p[14] + p[15];
    o[9]  = e[16] * invZ;
    o[10] = e[17] * invZ;
    o[11] = e[18] * invZ;

    float best = o[0]; int bi = 0; float acc = 0.f;
    #pragma unroll
    for (int k = 0; k < NC; ++k) {
        acc += o[k] * o[k];
        if (o[k] > best) { best = o[k]; bi = k; }  // strict > keeps first-max semantics
    }
    s2 = acc; pred = bi;
}

// ---- pass 1: per-class histogram count + per-class sum of s2, zero per-pixel atomics
__global__ __launch_bounds__(BLK) void msiwc_pass1(const float* __restrict__ x,
                                                   float* __restrict__ ws) {
    // per-thread register accumulators (all indices compile-time -> stays in VGPRs)
    float cnt[NC], sum[NC];
    #pragma unroll
    for (int k = 0; k < NC; ++k) { cnt[k] = 0.f; sum[k] = 0.f; }

    #pragma unroll
    for (int it = 0; it < ITERS; ++it) {
        unsigned chunk = (unsigned)it * (BLK * GRID) + blockIdx.x * BLK + threadIdx.x;
        unsigned p0 = chunk * 4u;
        unsigned n  = p0 >> 19;          // pixel / (H*W)
        unsigned hw = p0 & (HW - 1u);
        const float* base = x + (size_t)n * NCH * HW + hw;

        float4 v[NCH];
        #pragma unroll
        for (int c = 0; c < NCH; ++c)
            v[c] = *reinterpret_cast<const float4*>(base + (size_t)c * HW);

        #pragma unroll
        for (int j = 0; j < 4; ++j) {
            float pv[NCH];
            #pragma unroll
            for (int c = 0; c < NCH; ++c)
                pv[c] = (j == 0) ? v[c].x : (j == 1) ? v[c].y : (j == 2) ? v[c].z : v[c].w;
            float s2; int pred;
            pixel_eval(pv, s2, pred);
            #pragma unroll
            for (int k = 0; k < NC; ++k) {
                bool h = (pred == k);
                cnt[k] += h ? 1.0f : 0.0f;
                sum[k] += h ? s2   : 0.0f;
            }
        }
    }

    // block reduction: LDS transpose, 24 owner threads sum columns, 24 global atomics
    __shared__ float s_part[BLK * 2 * NC];   // 24 KB
    #pragma unroll
    for (int k = 0; k < NC; ++k) {
        s_part[threadIdx.x * 2 * NC + k]      = cnt[k];
        s_part[threadIdx.x * 2 * NC + NC + k] = sum[k];
    }
    __syncthreads();
    if (threadIdx.x < 2 * NC) {
        float a = 0.f;
        for (int t = 0; t < BLK; ++t) a += s_part[t * 2 * NC + threadIdx.x];
        atomicAdd(&ws[threadIdx.x], a);
    }
}

// ---- pass 2: weights from histogram, final scalar
__global__ void msiwc_pass2(const float* __restrict__ ws, float* __restrict__ out) {
    __shared__ float terms[NC];
    int k = threadIdx.x;
    if (k < NC) {
        double hist = (double)ws[k];
        double w = pow(hist, 0.2) * pow((double)NPIX, 0.8);
        if (w < 1.0) w = 1.0;
        terms[k] = (float)((double)ws[NC + k] / w);
    }
    __syncthreads();
    if (k == 0) {
        float tot = 0.f;
        #pragma unroll
        for (int i = 0; i < NC; ++i) tot += terms[i];
        out[0] = -tot / 48.0f;   // N*C = 4*12
    }
}

extern "C" void kernel_launch(void* const* d_in, const int* in_sizes, int n_in,
                              void* d_out, int out_size, void* d_ws, size_t ws_size,
                              hipStream_t stream) {
    const float* x = (const float*)d_in[0];
    float* ws = (float*)d_ws;

    // ws is poisoned once (0xAA) and NOT re-poisoned between graph replays:
    // zero the 24 accumulators every call.
    hipMemsetAsync(ws, 0, 2 * NC * sizeof(float), stream);

    msiwc_pass1<<<GRID, BLK, 0, stream>>>(x, ws);
    msiwc_pass2<<<1, 64, 0, stream>>>(ws, (float*)d_out);
}